// Round 5
// baseline (238.901 us; speedup 1.0000x reference)
//
#include <hip/hip_runtime.h>
#include <hip/hip_cooperative_groups.h>

#define HH 160
#define WW 160
#define DD 160
#define BB 4
#define NPB (HH * WW * DD / 4)   // 1,024,000 float4 per batch
#define K1B 256                   // min-pass blocks per batch
#define NTZ 10                    // z tiles (16 z each)
#define NTX 20                    // x tiles (8 x each)
#define NTY 20                    // y tiles (8 y each)
#define NTILES (BB * NTY * NTX * NTZ)   // 16000
#define GRID 1024                 // cooperative grid: 4 blocks/CU x 256 CU

typedef float vfloat4 __attribute__((ext_vector_type(4)));

// order-preserving float<->uint encode for unsigned atomicMin
__device__ __forceinline__ unsigned enc_f32(float f) {
    unsigned u = __float_as_uint(f);
    return u ^ ((u & 0x80000000u) ? 0xFFFFFFFFu : 0x80000000u);
}
__device__ __forceinline__ float dec_f32(unsigned e) {
    return __uint_as_float(e ^ ((e & 0x80000000u) ? 0x80000000u : 0xFFFFFFFFu));
}

// ---- conservative tile interval test (block-uniform, fp64) ----
__device__ __forceinline__ bool tile_may_be_valid(const double* c, int xt, int yt, int zt) {
    const double X0 = (double)(xt * 8), X1 = X0 + 7.0;
    const double Y0 = (double)(yt * 8), Y1 = Y0 + 7.0;
    const double Z0 = (double)(zt * 16), Z1 = Z0 + 15.0;
    double lo, hi, t;

    lo = c[3]; hi = c[3];
    t = c[0]; if (t >= 0.0) { lo += t * X0; hi += t * X1; } else { lo += t * X1; hi += t * X0; }
    t = c[1]; if (t >= 0.0) { lo += t * Y0; hi += t * Y1; } else { lo += t * Y1; hi += t * Y0; }
    t = c[2]; if (t >= 0.0) { lo += t * Z0; hi += t * Z1; } else { lo += t * Z1; hi += t * Z0; }
    if (hi < -1e-3 || lo > 159.001) return false;

    lo = c[7]; hi = c[7];
    t = c[4]; if (t >= 0.0) { lo += t * X0; hi += t * X1; } else { lo += t * X1; hi += t * X0; }
    t = c[5]; if (t >= 0.0) { lo += t * Y0; hi += t * Y1; } else { lo += t * Y1; hi += t * Y0; }
    t = c[6]; if (t >= 0.0) { lo += t * Z0; hi += t * Z1; } else { lo += t * Z1; hi += t * Z0; }
    if (hi < -1e-3 || lo > 159.001) return false;

    lo = c[11]; hi = c[11];
    t = c[8]; if (t >= 0.0) { lo += t * X0; hi += t * X1; } else { lo += t * X1; hi += t * X0; }
    t = c[9]; if (t >= 0.0) { lo += t * Y0; hi += t * Y1; } else { lo += t * Y1; hi += t * Y0; }
    t = c[10]; if (t >= 0.0) { lo += t * Z0; hi += t * Z1; } else { lo += t * Z1; hi += t * Z0; }
    if (hi < -1e-3 || lo > 159.001) return false;
    return true;
}

// ---- per-tile gather body (shared by coop + fallback paths) ----
// 256 threads cover one 8y x 8x x 16z tile: tz=tid&3 (z-quad), tx=(tid>>2)&7,
// ty=tid>>5. Per-voxel math bit-identical to the verified round-3 path; the
// two z-neighbor loads {z0,z1} are fused into one 8B load (same values:
// z0<=158 -> pair {z0,z0+1}; z0==159 -> load {158,159}, select v.y for both).
__device__ __forceinline__ void gather_tile(const float* __restrict__ img,
                                            const double* __restrict__ c,
                                            float fillv, int b, int xt, int yt, int zt,
                                            int tid, float* __restrict__ out)
{
    const int tz = tid & 3;
    const int tx = (tid >> 2) & 7;
    const int ty = tid >> 5;
    const int x = xt * 8 + tx;
    const int y = yt * 8 + ty;
    const int zq = zt * 16 + tz * 4;

    const double c2 = c[2], c6 = c[6], c10 = c[10];
    const double dx = (double)x, dy = (double)y, dz = (double)zq;
    double ixd = fma(c[0], dx, fma(c[1], dy, fma(c2, dz, c[3])));
    double iyd = fma(c[4], dx, fma(c[5], dy, fma(c6, dz, c[7])));
    double izd = fma(c[8], dx, fma(c[9], dy, fma(c10, dz, c[11])));

    // exact per-k validity prescan (sequential stepping, identical values to
    // the main loop, so no boundary-ulp disagreement)
    bool anyv = false;
    {
        double ax = ixd, ay = iyd, az = izd;
        #pragma unroll
        for (int k = 0; k < 4; k++) {
            anyv = anyv || ((ax >= 0.0) && (ax <= 159.0) && (ay >= 0.0) &&
                            (ay <= 159.0) && (az >= 0.0) && (az <= 159.0));
            ax += c2; ay += c6; az += c10;
        }
    }

    const float* base = img + (size_t)b * (HH * WW * DD);
    vfloat4 r;

    if (__any(anyv)) {
        #pragma unroll
        for (int k = 0; k < 4; k++) {
            const bool valid = (ixd >= 0.0) && (ixd <= 159.0) && (iyd >= 0.0) &&
                               (iyd <= 159.0) && (izd >= 0.0) && (izd <= 159.0);
            double flx = floor(ixd), fly = floor(iyd), flz = floor(izd);
            int x0 = (int)flx, y0 = (int)fly, z0 = (int)flz;
            x0 = min(max(x0, 0), 159);
            y0 = min(max(y0, 0), 159);
            z0 = min(max(z0, 0), 159);
            float fx = (float)(ixd - flx), fy = (float)(iyd - fly), fz = (float)(izd - flz);
            int x1 = min(x0 + 1, 159), y1 = min(y0 + 1, 159);
            const int zb = min(z0, 158);
            const bool ztop = (z0 == 159);
            const float* p00 = base + (y0 * WW + x0) * DD + zb;  // (y0, x0)
            const float* p10 = base + (y1 * WW + x0) * DD + zb;  // (y1, x0)
            const float* p01 = base + (y0 * WW + x1) * DD + zb;  // (y0, x1)
            const float* p11 = base + (y1 * WW + x1) * DD + zb;  // (y1, x1)
            float2 q00, q10, q01, q11;
            __builtin_memcpy(&q00, p00, 8);
            __builtin_memcpy(&q10, p10, 8);
            __builtin_memcpy(&q01, p01, 8);
            __builtin_memcpy(&q11, p11, 8);
            float v000 = ztop ? q00.y : q00.x, v001 = q00.y;
            float v010 = ztop ? q10.y : q10.x, v011 = q10.y;
            float v100 = ztop ? q01.y : q01.x, v101 = q01.y;
            float v110 = ztop ? q11.y : q11.x, v111 = q11.y;
            float wx0 = 1.0f - fx, wx1 = fx;
            float wy0 = 1.0f - fy, wy1 = fy;
            float wz0 = 1.0f - fz, wz1 = fz;
            // accumulate in the reference's (ox, oy, oz) loop order
            float acc;
            acc  = ((wx0 * wy0) * wz0) * v000;
            acc += ((wx0 * wy0) * wz1) * v001;
            acc += ((wx0 * wy1) * wz0) * v010;
            acc += ((wx0 * wy1) * wz1) * v011;
            acc += ((wx1 * wy0) * wz0) * v100;
            acc += ((wx1 * wy0) * wz1) * v101;
            acc += ((wx1 * wy1) * wz0) * v110;
            acc += ((wx1 * wy1) * wz1) * v111;
            r[k] = valid ? acc : fillv;
            ixd += c2; iyd += c6; izd += c10;
        }
    } else {
        r[0] = fillv; r[1] = fillv; r[2] = fillv; r[3] = fillv;
    }

    __builtin_nontemporal_store(r, (vfloat4*)(out + (size_t)((b * HH + y) * WW + x) * DD + zq));
}

// ---- cooperative fused kernel: min -> grid.sync -> fill/classify/gather ----
// Phase A: 1024 blocks = 256 per batch, each reads 64 KB (16 float4/thread),
// block-min -> atomicMin(encoded) into fillEnc[b] (memset-initialized 0xFF).
// Block 0 threads 0..3 compute fp64 affine constants.
// Phase B: grid-stride over 16000 tiles; non-survivor tiles write fill,
// survivor tiles (spread ~1/block by the stride) run the gather inline.
__global__ __launch_bounds__(256, 4) void fused_kernel(const float* __restrict__ img,
                                                       const float* __restrict__ transfos,
                                                       unsigned* __restrict__ fillEnc,
                                                       double* __restrict__ cst,
                                                       float* __restrict__ out) {
    const int bid = blockIdx.x;
    const int tid = threadIdx.x;

    // ---- phase A: per-batch min + affine constants ----
    {
        const float4* img4 = (const float4*)img;
        const int b = bid >> 8;
        const int bx = bid & 255;
        const size_t base = (size_t)b * NPB;
        const int t0 = bx * 256 + tid;   // < 65536
        const int S = K1B * 256;          // 65536

        float m = 3.4e38f;
        #pragma unroll
        for (int r = 0; r < 4; r++) {
            const int i0 = t0 + 4 * r * S;
            float4 v0 = img4[base + i0];
            float4 v1 = img4[base + i0 + S];
            float4 v2 = img4[base + i0 + 2 * S];
            float4 v3 = make_float4(3.4e38f, 3.4e38f, 3.4e38f, 3.4e38f);
            if (i0 + 3 * S < NPB) v3 = img4[base + i0 + 3 * S];   // only r==3 can fail
            m = fminf(m, fminf(fminf(v0.x, v0.y), fminf(v0.z, v0.w)));
            m = fminf(m, fminf(fminf(v1.x, v1.y), fminf(v1.z, v1.w)));
            m = fminf(m, fminf(fminf(v2.x, v2.y), fminf(v2.z, v2.w)));
            m = fminf(m, fminf(fminf(v3.x, v3.y), fminf(v3.z, v3.w)));
        }
        #pragma unroll
        for (int o = 32; o >= 1; o >>= 1) m = fminf(m, __shfl_down(m, o));
        __shared__ float s[4];
        if ((tid & 63) == 0) s[tid >> 6] = m;
        __syncthreads();
        if (tid == 0) {
            float bm = fminf(fminf(s[0], s[1]), fminf(s[2], s[3]));
            atomicMin(&fillEnc[b], enc_f32(bm));
        }

        if (bid == 0 && tid < BB) {
            const int bb = tid;
            const float* q = transfos + bb * 7;
            double x = q[0], y = q[1], z = q[2], w = q[3];
            double tx = 2.0 * x, ty = 2.0 * y, tz = 2.0 * z;
            double twx = tx * w, twy = ty * w, twz = tz * w;
            double txx = tx * x, txy = ty * x, txz = tz * x;
            double tyy = ty * y, tyz = tz * y, tzz = tz * z;
            double R[3][3] = {
                {1.0 - (tyy + tzz), txy - twz,         txz + twy},
                {txy + twz,         1.0 - (txx + tzz), tyz - twx},
                {txz - twy,         tyz + twx,         1.0 - (txx + tyy)}
            };
            double tr[3] = {(double)q[4], (double)q[5], (double)q[6]};
            for (int r = 0; r < 3; r++) {
                cst[bb * 12 + r * 4 + 0] = R[r][0];
                cst[bb * 12 + r * 4 + 1] = R[r][1];
                cst[bb * 12 + r * 4 + 2] = R[r][2];
                cst[bb * 12 + r * 4 + 3] = 79.5 * (tr[r] - R[r][0] - R[r][1] - R[r][2] + 1.0);
            }
        }
    }

    cooperative_groups::this_grid().sync();

    // ---- phase B: fill / classify / gather, grid-stride over tiles ----
    for (int t = bid; t < NTILES; t += GRID) {
        int zt = t % NTZ;
        int rr = t / NTZ;
        int xt = rr % NTX; rr /= NTX;
        int yt = rr % NTY;
        const int b = rr / NTY;
        const double* c = cst + b * 12;
        const float fillv = dec_f32(fillEnc[b]);

        if (tile_may_be_valid(c, xt, yt, zt)) {
            gather_tile(img, c, fillv, b, xt, yt, zt, tid, out);
        } else {
            vfloat4 v; v[0] = fillv; v[1] = fillv; v[2] = fillv; v[3] = fillv;
            const int tz = tid & 3;
            const int tx = (tid >> 2) & 7;
            const int ty = tid >> 5;
            const int x = xt * 8 + tx;
            const int y = yt * 8 + ty;
            const int zq = zt * 16 + tz * 4;
            __builtin_nontemporal_store(v, (vfloat4*)(out + (size_t)((b * HH + y) * WW + x) * DD + zq));
        }
    }
}

// ================== fallback path (non-cooperative), from round 4 ==================
__global__ __launch_bounds__(256) void min_cst_kernel(const float4* __restrict__ img4,
                                                      const float* __restrict__ transfos,
                                                      float* __restrict__ partial,
                                                      double* __restrict__ cst) {
    const int b = blockIdx.y;
    const size_t base = (size_t)b * NPB;
    const int t0 = blockIdx.x * 256 + threadIdx.x;
    const int S = K1B * 256;

    float m = 3.4e38f;
    #pragma unroll
    for (int r = 0; r < 4; r++) {
        const int i0 = t0 + 4 * r * S;
        float4 v0 = img4[base + i0];
        float4 v1 = img4[base + i0 + S];
        float4 v2 = img4[base + i0 + 2 * S];
        float4 v3 = make_float4(3.4e38f, 3.4e38f, 3.4e38f, 3.4e38f);
        if (i0 + 3 * S < NPB) v3 = img4[base + i0 + 3 * S];
        m = fminf(m, fminf(fminf(v0.x, v0.y), fminf(v0.z, v0.w)));
        m = fminf(m, fminf(fminf(v1.x, v1.y), fminf(v1.z, v1.w)));
        m = fminf(m, fminf(fminf(v2.x, v2.y), fminf(v2.z, v2.w)));
        m = fminf(m, fminf(fminf(v3.x, v3.y), fminf(v3.z, v3.w)));
    }
    #pragma unroll
    for (int o = 32; o >= 1; o >>= 1) m = fminf(m, __shfl_down(m, o));
    __shared__ float s[4];
    if ((threadIdx.x & 63) == 0) s[threadIdx.x >> 6] = m;
    __syncthreads();
    if (threadIdx.x == 0)
        partial[b * K1B + blockIdx.x] = fminf(fminf(s[0], s[1]), fminf(s[2], s[3]));

    if (blockIdx.x == 0 && blockIdx.y == 0 && threadIdx.x < BB) {
        const int bb = threadIdx.x;
        const float* q = transfos + bb * 7;
        double x = q[0], y = q[1], z = q[2], w = q[3];
        double tx = 2.0 * x, ty = 2.0 * y, tz = 2.0 * z;
        double twx = tx * w, twy = ty * w, twz = tz * w;
        double txx = tx * x, txy = ty * x, txz = tz * x;
        double tyy = ty * y, tyz = tz * y, tzz = tz * z;
        double R[3][3] = {
            {1.0 - (tyy + tzz), txy - twz,         txz + twy},
            {txy + twz,         1.0 - (txx + tzz), tyz - twx},
            {txz - twy,         tyz + twx,         1.0 - (txx + tyy)}
        };
        double t[3] = {(double)q[4], (double)q[5], (double)q[6]};
        for (int r = 0; r < 3; r++) {
            cst[bb * 12 + r * 4 + 0] = R[r][0];
            cst[bb * 12 + r * 4 + 1] = R[r][1];
            cst[bb * 12 + r * 4 + 2] = R[r][2];
            cst[bb * 12 + r * 4 + 3] = 79.5 * (t[r] - R[r][0] - R[r][1] - R[r][2] + 1.0);
        }
    }
}

__global__ __launch_bounds__(256) void fin_min_kernel(const float* __restrict__ partial,
                                                      float* __restrict__ fill) {
    const int wid = threadIdx.x >> 6, lane = threadIdx.x & 63;
    const float* p = partial + wid * K1B;
    float m = fminf(fminf(p[lane], p[lane + 64]), fminf(p[lane + 128], p[lane + 192]));
    #pragma unroll
    for (int o = 32; o >= 1; o >>= 1) m = fminf(m, __shfl_down(m, o));
    if (lane == 0) fill[wid] = m;
}

__global__ __launch_bounds__(256) void fill_kernel(const float* __restrict__ fill,
                                                   float* __restrict__ out) {
    const int b = blockIdx.y;
    const float fv = fill[b];
    vfloat4 v; v[0] = fv; v[1] = fv; v[2] = fv; v[3] = fv;
    vfloat4* o = (vfloat4*)(out + (size_t)b * (HH * WW * DD));
    const int stride = gridDim.x * 256;
    for (int i = blockIdx.x * 256 + threadIdx.x; i < NPB; i += stride)
        __builtin_nontemporal_store(v, o + i);
}

__global__ __launch_bounds__(256) void st3d_tile_kernel(const float* __restrict__ img,
                                                        const double* __restrict__ cst,
                                                        const float* __restrict__ fill,
                                                        float* __restrict__ out) {
    const int bzc = blockIdx.z;
    const int b = bzc / NTY;
    const int yt = bzc - b * NTY;
    const double* c = cst + b * 12;
    if (!tile_may_be_valid(c, blockIdx.y, yt, blockIdx.x)) return;
    gather_tile(img, c, fill[b], b, blockIdx.y, yt, blockIdx.x, threadIdx.x, out);
}

extern "C" void kernel_launch(void* const* d_in, const int* in_sizes, int n_in,
                              void* d_out, int out_size, void* d_ws, size_t ws_size,
                              hipStream_t stream) {
    const float* img = (const float*)d_in[0];
    const float* transfos = (const float*)d_in[1];
    float* out = (float*)d_out;

    // coop layout
    unsigned* fillEnc = (unsigned*)d_ws;                 // 16 B
    double* cstC = (double*)((char*)d_ws + 256);         // 384 B
    // fallback layout (disjoint)
    float* partial = (float*)((char*)d_ws + 4096);       // 4 KB
    double* cstF = (double*)((char*)d_ws + 9216);        // 384 B
    float* fillF = (float*)((char*)d_ws + 9728);         // 16 B

    hipMemsetAsync(d_ws, 0xFF, 16, stream);              // fillEnc = +inf keys

    void* args[] = { (void*)&img, (void*)&transfos, (void*)&fillEnc,
                     (void*)&cstC, (void*)&out };
    hipError_t err = hipLaunchCooperativeKernel((const void*)fused_kernel,
                                                dim3(GRID), dim3(256), args, 0, stream);
    if (err != hipSuccess) {
        // non-cooperative fallback (round-4 verified path)
        min_cst_kernel<<<dim3(K1B, BB), 256, 0, stream>>>((const float4*)img, transfos,
                                                          partial, cstF);
        fin_min_kernel<<<dim3(1), 256, 0, stream>>>(partial, fillF);
        fill_kernel<<<dim3(512, BB), 256, 0, stream>>>(fillF, out);
        st3d_tile_kernel<<<dim3(NTZ, NTX, NTY * BB), 256, 0, stream>>>(img, cstF,
                                                                       fillF, out);
    }
}

// Round 6
// 128.554 us; speedup vs baseline: 1.8584x; 1.8584x over previous
//
#include <hip/hip_runtime.h>

#define HH 160
#define WW 160
#define DD 160
#define BB 4
#define NPB (HH * WW * DD / 4)   // 1,024,000 float4 per batch
#define K1B 256                   // min-pass blocks per batch
#define NTZ 10                    // z tiles (16 z each)
#define NTX 20                    // x tiles (8 x each)
#define NTY 20                    // y tiles (8 y each)

typedef float vfloat4 __attribute__((ext_vector_type(4)));

// ---- kernel 1: per-batch block-partial min (NO atomics) + affine constants ----
// grid (256, BB) x 256. Each thread reads 16 float4 (4 rounds, MLP=4),
// stride 65536 float4. Block partial min -> partial[b*256 + bx].
// Block (0,0) threads 0..3 also compute fp64 affine constants:
//   ix = R00*x + R01*y + R02*z + 79.5*(t0 - R00 - R01 - R02 + 1)
// (exact fold of linspace + cx scaling, since 79.5*(2/159) == 1).
__global__ __launch_bounds__(256) void min_cst_kernel(const float4* __restrict__ img4,
                                                      const float* __restrict__ transfos,
                                                      float* __restrict__ partial,
                                                      double* __restrict__ cst) {
    const int b = blockIdx.y;
    const size_t base = (size_t)b * NPB;
    const int t0 = blockIdx.x * 256 + threadIdx.x;   // < 65536
    const int S = K1B * 256;                          // 65536

    float m = 3.4e38f;
    #pragma unroll
    for (int r = 0; r < 4; r++) {
        const int i0 = t0 + 4 * r * S;
        float4 v0 = img4[base + i0];
        float4 v1 = img4[base + i0 + S];
        float4 v2 = img4[base + i0 + 2 * S];
        float4 v3 = make_float4(3.4e38f, 3.4e38f, 3.4e38f, 3.4e38f);
        if (i0 + 3 * S < NPB) v3 = img4[base + i0 + 3 * S];   // only r==3 can fail
        m = fminf(m, fminf(fminf(v0.x, v0.y), fminf(v0.z, v0.w)));
        m = fminf(m, fminf(fminf(v1.x, v1.y), fminf(v1.z, v1.w)));
        m = fminf(m, fminf(fminf(v2.x, v2.y), fminf(v2.z, v2.w)));
        m = fminf(m, fminf(fminf(v3.x, v3.y), fminf(v3.z, v3.w)));
    }

    #pragma unroll
    for (int o = 32; o >= 1; o >>= 1) m = fminf(m, __shfl_down(m, o));
    __shared__ float s[4];
    if ((threadIdx.x & 63) == 0) s[threadIdx.x >> 6] = m;
    __syncthreads();
    if (threadIdx.x == 0)
        partial[b * K1B + blockIdx.x] = fminf(fminf(s[0], s[1]), fminf(s[2], s[3]));

    if (blockIdx.x == 0 && blockIdx.y == 0 && threadIdx.x < BB) {
        const int bb = threadIdx.x;
        const float* q = transfos + bb * 7;
        double x = q[0], y = q[1], z = q[2], w = q[3];
        double tx = 2.0 * x, ty = 2.0 * y, tz = 2.0 * z;
        double twx = tx * w, twy = ty * w, twz = tz * w;
        double txx = tx * x, txy = ty * x, txz = tz * x;
        double tyy = ty * y, tyz = tz * y, tzz = tz * z;
        double R[3][3] = {
            {1.0 - (tyy + tzz), txy - twz,         txz + twy},
            {txy + twz,         1.0 - (txx + tzz), tyz - twx},
            {txz - twy,         tyz + twx,         1.0 - (txx + tyy)}
        };
        double t[3] = {(double)q[4], (double)q[5], (double)q[6]};
        for (int r = 0; r < 3; r++) {
            cst[bb * 12 + r * 4 + 0] = R[r][0];
            cst[bb * 12 + r * 4 + 1] = R[r][1];
            cst[bb * 12 + r * 4 + 2] = R[r][2];
            cst[bb * 12 + r * 4 + 3] = 79.5 * (t[r] - R[r][0] - R[r][1] - R[r][2] + 1.0);
        }
    }
}

// ---- kernel 1b: final per-batch min (1 block, wave w reduces batch w) ----
__global__ __launch_bounds__(256) void fin_min_kernel(const float* __restrict__ partial,
                                                      float* __restrict__ fill) {
    const int wid = threadIdx.x >> 6, lane = threadIdx.x & 63;
    const float* p = partial + wid * K1B;
    float m = fminf(fminf(p[lane], p[lane + 64]), fminf(p[lane + 128], p[lane + 192]));
    #pragma unroll
    for (int o = 32; o >= 1; o >>= 1) m = fminf(m, __shfl_down(m, o));
    if (lane == 0) fill[wid] = m;
}

// ---- conservative tile interval test (block-uniform, fp64) ----
__device__ __forceinline__ bool tile_may_be_valid(const double* c, int xt, int yt, int zt) {
    const double X0 = (double)(xt * 8), X1 = X0 + 7.0;
    const double Y0 = (double)(yt * 8), Y1 = Y0 + 7.0;
    const double Z0 = (double)(zt * 16), Z1 = Z0 + 15.0;
    double lo, hi, t;

    lo = c[3]; hi = c[3];
    t = c[0]; if (t >= 0.0) { lo += t * X0; hi += t * X1; } else { lo += t * X1; hi += t * X0; }
    t = c[1]; if (t >= 0.0) { lo += t * Y0; hi += t * Y1; } else { lo += t * Y1; hi += t * Y0; }
    t = c[2]; if (t >= 0.0) { lo += t * Z0; hi += t * Z1; } else { lo += t * Z1; hi += t * Z0; }
    if (hi < -1e-3 || lo > 159.001) return false;

    lo = c[7]; hi = c[7];
    t = c[4]; if (t >= 0.0) { lo += t * X0; hi += t * X1; } else { lo += t * X1; hi += t * X0; }
    t = c[5]; if (t >= 0.0) { lo += t * Y0; hi += t * Y1; } else { lo += t * Y1; hi += t * Y0; }
    t = c[6]; if (t >= 0.0) { lo += t * Z0; hi += t * Z1; } else { lo += t * Z1; hi += t * Z0; }
    if (hi < -1e-3 || lo > 159.001) return false;

    lo = c[11]; hi = c[11];
    t = c[8]; if (t >= 0.0) { lo += t * X0; hi += t * X1; } else { lo += t * X1; hi += t * X0; }
    t = c[9]; if (t >= 0.0) { lo += t * Y0; hi += t * Y1; } else { lo += t * Y1; hi += t * Y0; }
    t = c[10]; if (t >= 0.0) { lo += t * Z0; hi += t * Z1; } else { lo += t * Z1; hi += t * Z0; }
    if (hi < -1e-3 || lo > 159.001) return false;
    return true;
}

// ---- per-tile gather body (verified round-5: z-paired 8B loads) ----
// 256 threads cover one 8y x 8x x 16z tile: tz=tid&3 (z-quad), tx=(tid>>2)&7,
// ty=tid>>5. Per-voxel math bit-identical to the verified round-3 path; the
// two z-neighbor loads {z0,z1} are fused into one 8B load (same values:
// z0<=158 -> pair {z0,z0+1}; z0==159 -> load {158,159}, select .y for both).
// This halves the scattered line-visit count (z0,z1 share a 64B line 15/16
// of the time), which is the dominant term in the gather's latency budget.
__device__ __forceinline__ void gather_tile(const float* __restrict__ img,
                                            const double* __restrict__ c,
                                            float fillv, int b, int xt, int yt, int zt,
                                            int tid, float* __restrict__ out)
{
    const int tz = tid & 3;
    const int tx = (tid >> 2) & 7;
    const int ty = tid >> 5;
    const int x = xt * 8 + tx;
    const int y = yt * 8 + ty;
    const int zq = zt * 16 + tz * 4;

    const double c2 = c[2], c6 = c[6], c10 = c[10];
    const double dx = (double)x, dy = (double)y, dz = (double)zq;
    double ixd = fma(c[0], dx, fma(c[1], dy, fma(c2, dz, c[3])));
    double iyd = fma(c[4], dx, fma(c[5], dy, fma(c6, dz, c[7])));
    double izd = fma(c[8], dx, fma(c[9], dy, fma(c10, dz, c[11])));

    // exact per-k validity prescan (sequential stepping, identical values to
    // the main loop, so no boundary-ulp disagreement)
    bool anyv = false;
    {
        double ax = ixd, ay = iyd, az = izd;
        #pragma unroll
        for (int k = 0; k < 4; k++) {
            anyv = anyv || ((ax >= 0.0) && (ax <= 159.0) && (ay >= 0.0) &&
                            (ay <= 159.0) && (az >= 0.0) && (az <= 159.0));
            ax += c2; ay += c6; az += c10;
        }
    }

    const float* base = img + (size_t)b * (HH * WW * DD);
    vfloat4 r;

    if (__any(anyv)) {
        #pragma unroll
        for (int k = 0; k < 4; k++) {
            const bool valid = (ixd >= 0.0) && (ixd <= 159.0) && (iyd >= 0.0) &&
                               (iyd <= 159.0) && (izd >= 0.0) && (izd <= 159.0);
            double flx = floor(ixd), fly = floor(iyd), flz = floor(izd);
            int x0 = (int)flx, y0 = (int)fly, z0 = (int)flz;
            x0 = min(max(x0, 0), 159);
            y0 = min(max(y0, 0), 159);
            z0 = min(max(z0, 0), 159);
            float fx = (float)(ixd - flx), fy = (float)(iyd - fly), fz = (float)(izd - flz);
            int x1 = min(x0 + 1, 159), y1 = min(y0 + 1, 159);
            const int zb = min(z0, 158);
            const bool ztop = (z0 == 159);
            const float* p00 = base + (y0 * WW + x0) * DD + zb;  // (y0, x0)
            const float* p10 = base + (y1 * WW + x0) * DD + zb;  // (y1, x0)
            const float* p01 = base + (y0 * WW + x1) * DD + zb;  // (y0, x1)
            const float* p11 = base + (y1 * WW + x1) * DD + zb;  // (y1, x1)
            float2 q00, q10, q01, q11;
            __builtin_memcpy(&q00, p00, 8);
            __builtin_memcpy(&q10, p10, 8);
            __builtin_memcpy(&q01, p01, 8);
            __builtin_memcpy(&q11, p11, 8);
            float v000 = ztop ? q00.y : q00.x, v001 = q00.y;
            float v010 = ztop ? q10.y : q10.x, v011 = q10.y;
            float v100 = ztop ? q01.y : q01.x, v101 = q01.y;
            float v110 = ztop ? q11.y : q11.x, v111 = q11.y;
            float wx0 = 1.0f - fx, wx1 = fx;
            float wy0 = 1.0f - fy, wy1 = fy;
            float wz0 = 1.0f - fz, wz1 = fz;
            // accumulate in the reference's (ox, oy, oz) loop order
            float acc;
            acc  = ((wx0 * wy0) * wz0) * v000;
            acc += ((wx0 * wy0) * wz1) * v001;
            acc += ((wx0 * wy1) * wz0) * v010;
            acc += ((wx0 * wy1) * wz1) * v011;
            acc += ((wx1 * wy0) * wz0) * v100;
            acc += ((wx1 * wy0) * wz1) * v101;
            acc += ((wx1 * wy1) * wz0) * v110;
            acc += ((wx1 * wy1) * wz1) * v111;
            r[k] = valid ? acc : fillv;
            ixd += c2; iyd += c6; izd += c10;
        }
    } else {
        r[0] = fillv; r[1] = fillv; r[2] = fillv; r[3] = fillv;
    }

    __builtin_nontemporal_store(r, (vfloat4*)(out + (size_t)((b * HH + y) * WW + x) * DD + zq));
}

// ---- kernel 2: merged fill + gather, one dispatch over all 16000 tiles ----
// Non-survivor tiles stream the fill value (pure BW work); survivor tiles run
// the gather (latency-bound work). Merging lets the fill's bandwidth phase
// execute UNDER the gather's latency-capped time instead of serially after it
// (round-1 showed fill rides nearly free: 45 us merged vs 44 us survivors-only).
// grid (NTZ, NTX, NTY*BB) x 256.
__global__ __launch_bounds__(256) void st3d_kernel(const float* __restrict__ img,
                                                   const double* __restrict__ cst,
                                                   const float* __restrict__ fill,
                                                   float* __restrict__ out) {
    const int bzc = blockIdx.z;
    const int b = bzc / NTY;
    const int yt = bzc - b * NTY;
    const int xt = blockIdx.y;
    const int zt = blockIdx.x;
    const double* c = cst + b * 12;
    const float fillv = fill[b];

    if (tile_may_be_valid(c, xt, yt, zt)) {
        gather_tile(img, c, fillv, b, xt, yt, zt, threadIdx.x, out);
    } else {
        vfloat4 v; v[0] = fillv; v[1] = fillv; v[2] = fillv; v[3] = fillv;
        const int tz = threadIdx.x & 3;
        const int tx = (threadIdx.x >> 2) & 7;
        const int ty = threadIdx.x >> 5;
        const int x = xt * 8 + tx;
        const int y = yt * 8 + ty;
        const int zq = zt * 16 + tz * 4;
        __builtin_nontemporal_store(v, (vfloat4*)(out + (size_t)((b * HH + y) * WW + x) * DD + zq));
    }
}

extern "C" void kernel_launch(void* const* d_in, const int* in_sizes, int n_in,
                              void* d_out, int out_size, void* d_ws, size_t ws_size,
                              hipStream_t stream) {
    const float* img = (const float*)d_in[0];
    const float* transfos = (const float*)d_in[1];
    float* out = (float*)d_out;
    float* partial = (float*)d_ws;                      // 1024 floats
    double* cst = (double*)((char*)d_ws + 4096);        // 48 doubles
    float* fill = (float*)((char*)d_ws + 8192);         // 4 floats

    min_cst_kernel<<<dim3(K1B, BB), 256, 0, stream>>>((const float4*)img, transfos,
                                                      partial, cst);
    fin_min_kernel<<<dim3(1), 256, 0, stream>>>(partial, fill);
    st3d_kernel<<<dim3(NTZ, NTX, NTY * BB), 256, 0, stream>>>(img, cst, fill, out);
}